// Round 3
// baseline (75.184 us; speedup 1.0000x reference)
//
#include <hip/hip_runtime.h>
#include <math.h>

// Problem constants (from setup_inputs: batch=1024, dim_z=32, n_samples=32, agg_size=256)
#define B    1024
#define D    32
#define NS   32
#define AGG  256
#define NC   (B / AGG)      // 4 chunks
#define M    (AGG * NS)     // 8192 samples per chunk
#define NJB  16             // j-blocks per (c,k)
#define JB   (M / NJB)      // 512 samples per block
#define TJ   (JB / 256)     // 2 samples per thread
#define NBLK (NC * D * NJB) // 2048 blocks -> 8 blocks/CU -> 32 waves/CU

// ws layout: [0]: uint counter | @256: float partial[NBLK] (8KB) | @16384: float4 params
// params[(c*D+k)*AGG + i] = {A, B, C, 0} with arg(z) = A*z^2 + B*z + C
//   = -0.5*log2e*((z-mu)^2*exp(-lv) + lv)
__global__ __launch_bounds__(256) void ksetup(const float* __restrict__ mean,
                                              const float* __restrict__ logvar,
                                              float4* __restrict__ params,
                                              unsigned* __restrict__ counter)
{
    constexpr float LOG2E = 1.4426950408889634f;
    const int id = blockIdx.x * 256 + threadIdx.x;  // ((c*D+k)*AGG + i)
    if (id == 0) counter[0] = 0u;                   // reset last-block counter each call
    const int i  = id & (AGG - 1);
    const int ck = id >> 8;          // c*D + k  (AGG=256)
    const int k  = ck & (D - 1);
    const int c  = ck >> 5;          // D=32
    const int row = c * AGG + i;
    const float mu = mean[row * D + k];
    const float lv = logvar[row * D + k];
    const float ev = __builtin_amdgcn_exp2f(-lv * LOG2E);   // exp(-lv), lv ~ N(0,1): safe
    params[id] = make_float4(-0.5f * LOG2E * ev,
                             LOG2E * mu * ev,
                             -0.5f * LOG2E * fmaf(mu * mu, ev, lv), 0.f);
}

template <bool USE_GP>
__global__ __launch_bounds__(256) void kmain(const float* __restrict__ mean,
                                             const float* __restrict__ logvar,
                                             const float* __restrict__ eps,
                                             const float4* __restrict__ params,
                                             float* __restrict__ partial,
                                             unsigned* __restrict__ counter,
                                             float* __restrict__ out)
{
    constexpr float LOG2E = 1.4426950408889634f;
    constexpr float LN2   = 0.6931471805599453f;
    const int bid = blockIdx.x;
    const int c   = bid / (D * NJB);
    const int rem = bid - c * (D * NJB);
    const int k   = rem / NJB;
    const int jb  = rem - k * NJB;
    const int j0  = jb * JB;
    const int t   = threadIdx.x;

    __shared__ float4 prm[AGG];
    const float4* __restrict__ pk = USE_GP ? (params + (c * D + k) * AGG) : prm;
    if (!USE_GP) {
        const int row  = c * AGG + t;     // thread t sets up component i=t
        const float mu = mean[row * D + k];
        const float lv = logvar[row * D + k];
        const float ev = __builtin_amdgcn_exp2f(-lv * LOG2E);
        prm[t] = make_float4(-0.5f * LOG2E * ev, LOG2E * mu * ev,
                             -0.5f * LOG2E * fmaf(mu * mu, ev, lv), 0.f);
        __syncthreads();
    }

    // z for this thread's TJ samples (z2 flat layout == eps flat layout)
    float zv[TJ], acc[TJ];
#pragma unroll
    for (int u = 0; u < TJ; ++u) {
        const int j   = j0 + t + 256 * u;
        const int row = c * AGG + (j >> 5);          // this sample's own component
        const float mu = mean[row * D + k];
        const float lv = logvar[row * D + k];
        const float sd = __builtin_amdgcn_exp2f(0.5f * LOG2E * lv);  // exp(0.5*lv)
        const float e  = eps[(size_t)(c * M + j) * D + k];
        zv[u]  = fmaf(e, sd, mu);
        acc[u] = 0.f;
    }

    // Pairwise loop over 256 components. pk[i] wave-uniform -> scalar loads.
    // Per (i,u): 2 v_fma + 1 v_add (VALU, 6 cyc) + 1 v_exp (trans, 8 cyc) -> trans-bound.
#pragma unroll 8
    for (int i = 0; i < AGG; ++i) {
        const float4 p = pk[i];
#pragma unroll
        for (int u = 0; u < TJ; ++u) {
            const float arg = fmaf(fmaf(p.x, zv[u], p.y), zv[u], p.z);
            acc[u] += __builtin_amdgcn_exp2f(arg);
        }
    }

    // per-thread contribution: ln(sum_i) + 0.5*z^2 (global constants folded at the end)
    float r = 0.f;
#pragma unroll
    for (int u = 0; u < TJ; ++u)
        r += LN2 * log2f(acc[u]) + 0.5f * zv[u] * zv[u];

    // deterministic block reduction
    for (int off = 32; off > 0; off >>= 1) r += __shfl_down(r, off, 64);
    __shared__ float wsum[4];
    if ((t & 63) == 0) wsum[t >> 6] = r;
    __syncthreads();

    // last-block final reduction (deterministic: fixed-order sum over partial[])
    __shared__ int isLast;
    if (t == 0) {
        partial[bid] = (wsum[0] + wsum[1]) + (wsum[2] + wsum[3]);
        __threadfence();                          // publish partial device-wide
        const unsigned old = atomicAdd(counter, 1u);
        isLast = (old == (unsigned)(NBLK - 1));
    }
    __syncthreads();
    if (isLast) {
        __threadfence();                          // acquire all partials
        double s = 0.0;
#pragma unroll
        for (int i = 0; i < NBLK / 256; ++i) s += (double)partial[i * 256 + t];
        __shared__ double sd[256];
        sd[t] = s;
        __syncthreads();
        for (int off = 128; off > 0; off >>= 1) {
            if (t < off) sd[t] += sd[t + off];
            __syncthreads();
        }
        if (t == 0) {
            // out = total/(nc*M) - D*ln(256)
            out[0] = (float)(sd[0] * (1.0 / (double)(NC * M))
                             - (double)D * 5.545177444479562);
        }
    }
}

extern "C" void kernel_launch(void* const* d_in, const int* in_sizes, int n_in,
                              void* d_out, int out_size, void* d_ws, size_t ws_size,
                              hipStream_t stream)
{
    const float* mean   = (const float*)d_in[0];
    const float* logvar = (const float*)d_in[1];
    const float* eps    = (const float*)d_in[2];
    float* out = (float*)d_out;

    unsigned* counter = (unsigned*)d_ws;
    float*    partial = (float*)((char*)d_ws + 256);        // NBLK floats = 8KB
    float4*   params  = (float4*)((char*)d_ws + 16384);     // 512KB param table
    const bool use_gp = ws_size >= (size_t)16384 + sizeof(float4) * NC * D * AGG;

    if (use_gp) {
        ksetup<<<(NC * D * AGG) / 256, 256, 0, stream>>>(mean, logvar, params, counter);
        kmain<true><<<NBLK, 256, 0, stream>>>(mean, logvar, eps, params, partial,
                                              counter, out);
    } else {
        // LDS param path still needs the counter zeroed: reuse ksetup's params slot
        // only if present; zero counter with a tiny launch via ksetup is unavailable,
        // so fall back to a 3-launch-free path: zero counter in a 1-block helper.
        hipMemsetAsync(counter, 0, sizeof(unsigned), stream);
        kmain<false><<<NBLK, 256, 0, stream>>>(mean, logvar, eps, nullptr, partial,
                                               counter, out);
    }
}

// Round 4
// 57.312 us; speedup vs baseline: 1.3118x; 1.3118x over previous
//
#include <hip/hip_runtime.h>
#include <math.h>

// Problem constants (from setup_inputs: batch=1024, dim_z=32, n_samples=32, agg_size=256)
#define B    1024
#define D    32
#define NS   32
#define AGG  256
#define NC   (B / AGG)      // 4 chunks
#define M    (AGG * NS)     // 8192 samples per chunk
#define NJB  16             // j-blocks per (c,k)
#define JB   (M / NJB)      // 512 samples per block
#define TJ   (JB / 256)     // 2 samples per thread
#define NBLK (NC * D * NJB) // 2048 blocks -> 8 blocks/CU -> 32 waves/CU

// ws layout: [0]: uint counter | @256: float partial[NBLK] (8KB)
__global__ void kzero(unsigned* __restrict__ counter) { counter[0] = 0u; }

__global__ __launch_bounds__(256) void kmain(const float* __restrict__ mean,
                                             const float* __restrict__ logvar,
                                             const float* __restrict__ eps,
                                             float* __restrict__ partial,
                                             unsigned* __restrict__ counter,
                                             float* __restrict__ out)
{
    constexpr float LOG2E = 1.4426950408889634f;
    constexpr float LN2   = 0.6931471805599453f;
    const int bid = blockIdx.x;
    const int c   = bid / (D * NJB);
    const int rem = bid - c * (D * NJB);
    const int k   = rem / NJB;
    const int jb  = rem - k * NJB;
    const int j0  = jb * JB;
    const int t   = threadIdx.x;

    // Stage this (c,k)'s 256-component param table in LDS: thread t = component t.
    // arg(z) = A*z^2 + B*z + C = -0.5*log2e*((z-mu)^2*exp(-lv) + lv)
    __shared__ float4 prm[AGG];
    {
        const int row  = c * AGG + t;
        const float mu = mean[row * D + k];
        const float lv = logvar[row * D + k];
        const float ev = __builtin_amdgcn_exp2f(-lv * LOG2E);   // exp(-lv), lv~N(0,1): safe
        prm[t] = make_float4(-0.5f * LOG2E * ev,
                             LOG2E * mu * ev,
                             -0.5f * LOG2E * fmaf(mu * mu, ev, lv), 0.f);
    }
    __syncthreads();

    // z for this thread's TJ samples (z2 flat layout == eps flat layout)
    float zv[TJ], acc[TJ];
#pragma unroll
    for (int u = 0; u < TJ; ++u) {
        const int j   = j0 + t + 256 * u;
        const int row = c * AGG + (j >> 5);          // this sample's own component
        const float mu = mean[row * D + k];
        const float lv = logvar[row * D + k];
        const float sd = __builtin_amdgcn_exp2f(0.5f * LOG2E * lv);  // exp(0.5*lv)
        const float e  = eps[(size_t)(c * M + j) * D + k];
        zv[u]  = fmaf(e, sd, mu);
        acc[u] = 0.f;
    }

    // Pairwise loop over 256 components. prm[i] is wave-uniform -> LDS broadcast
    // (no bank conflict, no scalar-cache traffic). Per (i,u) unit:
    // 2 v_fma + 1 v_add (6 cyc VALU) + 1 v_exp (8 cyc trans) + 6 cyc LDS -> trans-bound.
#pragma unroll 8
    for (int i = 0; i < AGG; ++i) {
        const float4 p = prm[i];
#pragma unroll
        for (int u = 0; u < TJ; ++u) {
            const float arg = fmaf(fmaf(p.x, zv[u], p.y), zv[u], p.z);
            acc[u] += __builtin_amdgcn_exp2f(arg);
        }
    }

    // per-thread contribution: ln(sum_i) + 0.5*z^2 (global constants folded at the end)
    float r = 0.f;
#pragma unroll
    for (int u = 0; u < TJ; ++u)
        r += LN2 * log2f(acc[u]) + 0.5f * zv[u] * zv[u];

    // deterministic block reduction
    for (int off = 32; off > 0; off >>= 1) r += __shfl_down(r, off, 64);
    __shared__ float wsum[4];
    if ((t & 63) == 0) wsum[t >> 6] = r;
    __syncthreads();

    // last-block final reduction (deterministic: fixed-order sum over partial[])
    __shared__ int isLast;
    if (t == 0) {
        partial[bid] = (wsum[0] + wsum[1]) + (wsum[2] + wsum[3]);
        __threadfence();                          // publish partial device-wide
        const unsigned old = atomicAdd(counter, 1u);
        isLast = (old == (unsigned)(NBLK - 1));
    }
    __syncthreads();
    if (isLast) {
        __threadfence();                          // acquire all partials
        double s = 0.0;
#pragma unroll
        for (int i = 0; i < NBLK / 256; ++i) s += (double)partial[i * 256 + t];
        __shared__ double sd[256];
        sd[t] = s;
        __syncthreads();
        for (int off = 128; off > 0; off >>= 1) {
            if (t < off) sd[t] += sd[t + off];
            __syncthreads();
        }
        if (t == 0) {
            // out = total/(nc*M) - D*ln(256)
            out[0] = (float)(sd[0] * (1.0 / (double)(NC * M))
                             - (double)D * 5.545177444479562);
        }
    }
}

extern "C" void kernel_launch(void* const* d_in, const int* in_sizes, int n_in,
                              void* d_out, int out_size, void* d_ws, size_t ws_size,
                              hipStream_t stream)
{
    const float* mean   = (const float*)d_in[0];
    const float* logvar = (const float*)d_in[1];
    const float* eps    = (const float*)d_in[2];
    float* out = (float*)d_out;

    unsigned* counter = (unsigned*)d_ws;
    float*    partial = (float*)((char*)d_ws + 256);   // NBLK floats = 8KB

    kzero<<<1, 64, 0, stream>>>(counter);
    kmain<<<NBLK, 256, 0, stream>>>(mean, logvar, eps, partial, counter, out);
}

// Round 5
// 51.202 us; speedup vs baseline: 1.4684x; 1.1193x over previous
//
#include <hip/hip_runtime.h>
#include <math.h>

// Problem constants (from setup_inputs: batch=1024, dim_z=32, n_samples=32, agg_size=256)
#define B    1024
#define D    32
#define NS   32
#define AGG  256
#define NC   (B / AGG)      // 4 chunks
#define M    (AGG * NS)     // 8192 samples per chunk
#define NJB  8              // j-blocks per (c,k)
#define JB   (M / NJB)      // 1024 samples per block
#define TJ   (JB / 256)     // 4 samples per thread
#define NBLK (NC * D * NJB) // 1024 blocks -> 4 blocks/CU -> 16 waves/CU

// ws layout: [0]: uint counter | @256: float partial[NBLK] (4KB) | @8192: float4 params
// params[(c*D+k)*AGG + i] = {A, B, C, sd}:
//   arg(z) = A*z^2 + B*z + C = -0.5*log2e*((z-mu)^2*exp(-lv) + lv),  sd = exp(0.5*lv)
//   (mu is recoverable as -0.5*B/A)
__global__ __launch_bounds__(256) void ksetup(const float* __restrict__ mean,
                                              const float* __restrict__ logvar,
                                              float4* __restrict__ params,
                                              unsigned* __restrict__ counter)
{
    constexpr float LOG2E = 1.4426950408889634f;
    const int tid = blockIdx.x * 256 + threadIdx.x;   // over B*D = 32768, k fastest
    if (tid == 0) counter[0] = 0u;                    // reset last-block counter
    const int row = tid >> 5;        // 0..1023  (global component row)
    const int k   = tid & (D - 1);
    const int c   = row >> 8;
    const int i   = row & (AGG - 1);
    // coalesced reads (k fastest); scattered 16B store (fire-and-forget)
    const float mu = mean[tid];
    const float lv = logvar[tid];
    const float ev = __builtin_amdgcn_exp2f(-lv * LOG2E);      // exp(-lv); lv~N(0,1): safe
    params[((c * D + k) << 8) | i] =
        make_float4(-0.5f * LOG2E * ev,
                    LOG2E * mu * ev,
                    -0.5f * LOG2E * fmaf(mu * mu, ev, lv),
                    __builtin_amdgcn_exp2f(0.5f * LOG2E * lv)); // sd = exp(0.5*lv)
}

__global__ __launch_bounds__(256) void kmain(const float* __restrict__ eps,
                                             const float4* __restrict__ params,
                                             float* __restrict__ partial,
                                             unsigned* __restrict__ counter,
                                             float* __restrict__ out)
{
    constexpr float LN2 = 0.6931471805599453f;
    const int bid = blockIdx.x;
    const int c   = bid / (D * NJB);
    const int rem = bid - c * (D * NJB);
    const int k   = rem / NJB;
    const int jb  = rem - k * NJB;
    const int j0  = jb * JB;
    const int t   = threadIdx.x;

    // Stage this (c,k)'s param table: ONE coalesced float4 load -> LDS.
    __shared__ float4 prm[AGG];
    prm[t] = params[((c * D + k) << 8) | t];
    __syncthreads();

    // z for this thread's TJ samples (z2 flat layout == eps flat layout).
    // mu = -0.5*B/A, sd stored in .w — no mean/logvar access here.
    float zv[TJ], acc[TJ];
#pragma unroll
    for (int u = 0; u < TJ; ++u) {
        const int j    = j0 + t + 256 * u;
        const float4 p = prm[j >> 5];                 // own component (wave-uniform-ish)
        const float mu = -0.5f * p.y * __builtin_amdgcn_rcpf(p.x);
        const float e  = eps[(size_t)(c * M + j) * D + k];
        zv[u]  = fmaf(e, p.w, mu);
        acc[u] = 0.f;
    }

    // Pairwise loop over 256 components. prm[i] wave-uniform -> LDS broadcast.
    // Per (i,u): 2 v_fma + 1 v_add (6 cyc) + 1 v_exp (8 cyc, 1/4-rate VALU) = 14 cyc.
#pragma unroll 4
    for (int i = 0; i < AGG; ++i) {
        const float4 p = prm[i];
#pragma unroll
        for (int u = 0; u < TJ; ++u) {
            const float arg = fmaf(fmaf(p.x, zv[u], p.y), zv[u], p.z);
            acc[u] += __builtin_amdgcn_exp2f(arg);
        }
    }

    // per-thread contribution: ln(sum_i) + 0.5*z^2 (global constants folded at the end)
    float r = 0.f;
#pragma unroll
    for (int u = 0; u < TJ; ++u)
        r += LN2 * log2f(acc[u]) + 0.5f * zv[u] * zv[u];

    // deterministic block reduction
    for (int off = 32; off > 0; off >>= 1) r += __shfl_down(r, off, 64);
    __shared__ float wsum[4];
    if ((t & 63) == 0) wsum[t >> 6] = r;
    __syncthreads();

    // last-block final reduction (deterministic: fixed-order sum over partial[])
    __shared__ int isLast;
    if (t == 0) {
        partial[bid] = (wsum[0] + wsum[1]) + (wsum[2] + wsum[3]);
        __threadfence();                          // publish partial device-wide
        const unsigned old = atomicAdd(counter, 1u);
        isLast = (old == (unsigned)(NBLK - 1));
    }
    __syncthreads();
    if (isLast) {
        __threadfence();                          // acquire all partials
        double s = 0.0;
#pragma unroll
        for (int i = 0; i < NBLK / 256; ++i) s += (double)partial[i * 256 + t];
        __shared__ double sd[256];
        sd[t] = s;
        __syncthreads();
        for (int off = 128; off > 0; off >>= 1) {
            if (t < off) sd[t] += sd[t + off];
            __syncthreads();
        }
        if (t == 0) {
            // out = total/(nc*M) - D*ln(256)
            out[0] = (float)(sd[0] * (1.0 / (double)(NC * M))
                             - (double)D * 5.545177444479562);
        }
    }
}

extern "C" void kernel_launch(void* const* d_in, const int* in_sizes, int n_in,
                              void* d_out, int out_size, void* d_ws, size_t ws_size,
                              hipStream_t stream)
{
    const float* mean   = (const float*)d_in[0];
    const float* logvar = (const float*)d_in[1];
    const float* eps    = (const float*)d_in[2];
    float* out = (float*)d_out;

    unsigned* counter = (unsigned*)d_ws;
    float*    partial = (float*)((char*)d_ws + 256);    // NBLK floats = 4KB
    float4*   params  = (float4*)((char*)d_ws + 8192);  // 512KB param table

    ksetup<<<(B * D) / 256, 256, 0, stream>>>(mean, logvar, params, counter);
    kmain<<<NBLK, 256, 0, stream>>>(eps, params, partial, counter, out);
}

// Round 6
// 50.283 us; speedup vs baseline: 1.4952x; 1.0183x over previous
//
#include <hip/hip_runtime.h>
#include <math.h>

// Problem constants (from setup_inputs: batch=1024, dim_z=32, n_samples=32, agg_size=256)
#define B    1024
#define D    32
#define NS   32
#define AGG  256
#define NC   (B / AGG)      // 4 chunks
#define M    (AGG * NS)     // 8192 samples per chunk
#define NJB  4              // j-blocks per (c,k)
#define JB   (M / NJB)      // 2048 samples per block
#define TJ   (JB / 256)     // 8 samples per thread
#define NBLK (NC * D * NJB) // 512 blocks -> 2 blocks/CU -> 8 waves/CU

typedef float v2f __attribute__((ext_vector_type(2)));

// ws layout: [0]: uint counter | @256: float partial[NBLK] (2KB) | @8192: float4 params
// params[(c*D+k)*AGG + i] = {A, B, C, sd}:
//   arg(z) = A*z^2 + B*z + C = -0.5*log2e*((z-mu)^2*exp(-lv) + lv),  sd = exp(0.5*lv)
//   (mu recoverable as -0.5*B/A)
__global__ __launch_bounds__(256) void ksetup(const float* __restrict__ mean,
                                              const float* __restrict__ logvar,
                                              float4* __restrict__ params,
                                              unsigned* __restrict__ counter)
{
    constexpr float LOG2E = 1.4426950408889634f;
    const int tid = blockIdx.x * 256 + threadIdx.x;   // over B*D = 32768, k fastest
    if (tid == 0) counter[0] = 0u;                    // reset last-block counter
    const int row = tid >> 5;        // 0..1023  (global component row)
    const int k   = tid & (D - 1);
    const int c   = row >> 8;
    const int i   = row & (AGG - 1);
    const float mu = mean[tid];      // coalesced
    const float lv = logvar[tid];
    const float ev = __builtin_amdgcn_exp2f(-lv * LOG2E);      // exp(-lv); lv~N(0,1): safe
    params[((c * D + k) << 8) | i] =
        make_float4(-0.5f * LOG2E * ev,
                    LOG2E * mu * ev,
                    -0.5f * LOG2E * fmaf(mu * mu, ev, lv),
                    __builtin_amdgcn_exp2f(0.5f * LOG2E * lv)); // sd = exp(0.5*lv)
}

__global__ __launch_bounds__(256) void kmain(const float* __restrict__ eps,
                                             const float4* __restrict__ params,
                                             float* __restrict__ partial,
                                             unsigned* __restrict__ counter,
                                             float* __restrict__ out)
{
    constexpr float LN2 = 0.6931471805599453f;
    const int bid = blockIdx.x;
    const int c   = bid / (D * NJB);
    const int rem = bid - c * (D * NJB);
    const int k   = rem / NJB;
    const int jb  = rem - k * NJB;
    const int j0  = jb * JB;
    const int t   = threadIdx.x;

    // Stage this (c,k)'s param table: ONE coalesced float4 load -> LDS.
    __shared__ float4 prm[AGG];
    prm[t] = params[((c * D + k) << 8) | t];
    __syncthreads();

    // z for this thread's TJ samples (z2 flat layout == eps flat layout).
    float zv[TJ];
    v2f accv[TJ / 2];
#pragma unroll
    for (int u = 0; u < TJ; ++u) {
        const int j    = j0 + t + 256 * u;
        const float4 p = prm[j >> 5];                 // own component
        const float mu = -0.5f * p.y * __builtin_amdgcn_rcpf(p.x);
        const float e  = eps[(size_t)(c * M + j) * D + k];
        zv[u] = fmaf(e, p.w, mu);
    }
    v2f zp[TJ / 2];
#pragma unroll
    for (int q = 0; q < TJ / 2; ++q) {
        zp[q]   = (v2f){zv[2 * q], zv[2 * q + 1]};
        accv[q] = (v2f){0.f, 0.f};
    }

    // Pairwise loop over 256 components. prm[i] wave-uniform -> one ds_read_b128
    // broadcast feeding 8 exps. Packed math: (A*z+B)*z+C contracts to 2 v_pk_fma_f32
    // per pair; acc += is v_pk_add_f32. Per pair: 3 pk-VALU (6 cyc) + 2 v_exp (16 cyc).
#pragma unroll 2
    for (int i = 0; i < AGG; ++i) {
        const float4 p = prm[i];
        const v2f A2 = (v2f){p.x, p.x};
        const v2f B2 = (v2f){p.y, p.y};
        const v2f C2 = (v2f){p.z, p.z};
#pragma unroll
        for (int q = 0; q < TJ / 2; ++q) {
            const v2f arg = (A2 * zp[q] + B2) * zp[q] + C2;
            accv[q] += (v2f){__builtin_amdgcn_exp2f(arg.x),
                             __builtin_amdgcn_exp2f(arg.y)};
        }
    }

    // per-thread contribution: ln(sum_i) + 0.5*z^2 (global constants folded at the end)
    float r = 0.f;
#pragma unroll
    for (int q = 0; q < TJ / 2; ++q) {
        r += LN2 * __builtin_amdgcn_logf(accv[q].x) + 0.5f * zp[q].x * zp[q].x;
        r += LN2 * __builtin_amdgcn_logf(accv[q].y) + 0.5f * zp[q].y * zp[q].y;
    }

    // deterministic block reduction
    for (int off = 32; off > 0; off >>= 1) r += __shfl_down(r, off, 64);
    __shared__ float wsum[4];
    if ((t & 63) == 0) wsum[t >> 6] = r;
    __syncthreads();

    // last-block final reduction (deterministic: fixed-order sum over partial[])
    __shared__ int isLast;
    if (t == 0) {
        partial[bid] = (wsum[0] + wsum[1]) + (wsum[2] + wsum[3]);
        __threadfence();                          // publish partial device-wide
        const unsigned old = atomicAdd(counter, 1u);
        isLast = (old == (unsigned)(NBLK - 1));
    }
    __syncthreads();
    if (isLast) {
        __threadfence();                          // acquire all partials
        double s = 0.0;
#pragma unroll
        for (int i = 0; i < NBLK / 256; ++i) s += (double)partial[i * 256 + t];
        __shared__ double sd[256];
        sd[t] = s;
        __syncthreads();
        for (int off = 128; off > 0; off >>= 1) {
            if (t < off) sd[t] += sd[t + off];
            __syncthreads();
        }
        if (t == 0) {
            // out = total/(nc*M) - D*ln(256)
            out[0] = (float)(sd[0] * (1.0 / (double)(NC * M))
                             - (double)D * 5.545177444479562);
        }
    }
}

extern "C" void kernel_launch(void* const* d_in, const int* in_sizes, int n_in,
                              void* d_out, int out_size, void* d_ws, size_t ws_size,
                              hipStream_t stream)
{
    const float* mean   = (const float*)d_in[0];
    const float* logvar = (const float*)d_in[1];
    const float* eps    = (const float*)d_in[2];
    float* out = (float*)d_out;

    unsigned* counter = (unsigned*)d_ws;
    float*    partial = (float*)((char*)d_ws + 256);    // NBLK floats
    float4*   params  = (float4*)((char*)d_ws + 8192);  // 512KB param table

    ksetup<<<(B * D) / 256, 256, 0, stream>>>(mean, logvar, params, counter);
    kmain<<<NBLK, 256, 0, stream>>>(eps, params, partial, counter, out);
}

// Round 7
// 49.236 us; speedup vs baseline: 1.5270x; 1.0213x over previous
//
#include <hip/hip_runtime.h>
#include <math.h>

// Problem constants (from setup_inputs: batch=1024, dim_z=32, n_samples=32, agg_size=256)
#define B    1024
#define D    32
#define NS   32
#define AGG  256
#define NC   (B / AGG)      // 4 chunks
#define M    (AGG * NS)     // 8192 samples per chunk
#define NJB  4              // j-blocks per (c,k)
#define JB   (M / NJB)      // 2048 samples per block
#define TJ   (JB / 256)     // 8 samples per thread
#define NBLK (NC * D * NJB) // 512 blocks -> 2 blocks/CU -> 8 waves/CU

typedef float v2f __attribute__((ext_vector_type(2)));

// ws layout: [0]: uint counter | @256: float partial[NBLK] (2KB) | @8192: float4 params
// params[(c*D+k)*AGG + i] = {A, B, C, sd}:
//   arg(z) = A*z^2 + B*z + C = -0.5*log2e*((z-mu)^2*exp(-lv) + lv),  sd = exp(0.5*lv)
//   (mu recoverable as -0.5*B/A)
__global__ __launch_bounds__(256) void ksetup(const float* __restrict__ mean,
                                              const float* __restrict__ logvar,
                                              float4* __restrict__ params,
                                              unsigned* __restrict__ counter)
{
    constexpr float LOG2E = 1.4426950408889634f;
    const int tid = blockIdx.x * 256 + threadIdx.x;   // over B*D = 32768, k fastest
    if (tid == 0) counter[0] = 0u;                    // reset last-block counter
    const int row = tid >> 5;        // 0..1023  (global component row)
    const int k   = tid & (D - 1);
    const int c   = row >> 8;
    const int i   = row & (AGG - 1);
    const float mu = mean[tid];      // coalesced
    const float lv = logvar[tid];
    const float ev = __builtin_amdgcn_exp2f(-lv * LOG2E);      // exp(-lv); lv~N(0,1): safe
    params[((c * D + k) << 8) | i] =
        make_float4(-0.5f * LOG2E * ev,
                    LOG2E * mu * ev,
                    -0.5f * LOG2E * fmaf(mu * mu, ev, lv),
                    __builtin_amdgcn_exp2f(0.5f * LOG2E * lv)); // sd = exp(0.5*lv)
}

__global__ __launch_bounds__(256) void kmain(const float* __restrict__ eps,
                                             const float4* __restrict__ params,
                                             float* __restrict__ partial,
                                             unsigned* __restrict__ counter,
                                             float* __restrict__ out)
{
    constexpr float LN2 = 0.6931471805599453f;
    const int bid = blockIdx.x;
    const int c   = bid / (D * NJB);
    const int rem = bid - c * (D * NJB);
    const int k   = rem / NJB;
    const int jb  = rem - k * NJB;
    const int j0  = jb * JB;
    const int t   = threadIdx.x;

    // Issue the scattered eps gathers FIRST (their ~L2 latency hides under staging).
    float ev[TJ];
#pragma unroll
    for (int u = 0; u < TJ; ++u)
        ev[u] = eps[(size_t)(c * M + j0 + t + 256 * u) * D + k];

    // Stage this (c,k)'s param table: ONE coalesced float4 load -> LDS.
    __shared__ float4 prm[AGG];
    prm[t] = params[((c * D + k) << 8) | t];
    __syncthreads();

    // z for this thread's TJ samples (z2 flat layout == eps flat layout).
    float zv[TJ];
#pragma unroll
    for (int u = 0; u < TJ; ++u) {
        const float4 p = prm[(j0 + t + 256 * u) >> 5];   // own component
        const float mu = -0.5f * p.y * __builtin_amdgcn_rcpf(p.x);
        zv[u] = fmaf(ev[u], p.w, mu);
    }
    v2f zp[TJ / 2], accv[TJ / 2];
#pragma unroll
    for (int q = 0; q < TJ / 2; ++q) {
        zp[q]   = (v2f){zv[2 * q], zv[2 * q + 1]};
        accv[q] = (v2f){0.f, 0.f};
    }

    // Pairwise loop over 256 components with explicit distance-2 register prefetch:
    // ds_read for i+2/i+3 issues before ~176 cyc of compute on i/i+1, covering the
    // ~120 cyc LDS latency. Per pair: 2 v_pk_fma + 1 v_pk_add (6 cyc) + 2 v_exp (16 cyc).
    auto body = [&](const float4 p) {
        const v2f A2 = (v2f){p.x, p.x};
        const v2f B2 = (v2f){p.y, p.y};
        const v2f C2 = (v2f){p.z, p.z};
#pragma unroll
        for (int q = 0; q < TJ / 2; ++q) {
            const v2f arg = (A2 * zp[q] + B2) * zp[q] + C2;
            accv[q] += (v2f){__builtin_amdgcn_exp2f(arg.x),
                             __builtin_amdgcn_exp2f(arg.y)};
        }
    };
    float4 pa = prm[0], pb = prm[1];
#pragma unroll 2
    for (int i = 0; i < AGG - 2; i += 2) {
        const float4 na = prm[i + 2];
        const float4 nb = prm[i + 3];
        body(pa);
        body(pb);
        pa = na;
        pb = nb;
    }
    body(pa);
    body(pb);

    // per-thread contribution: ln(sum_i) + 0.5*z^2 (global constants folded at the end)
    float r = 0.f;
#pragma unroll
    for (int q = 0; q < TJ / 2; ++q) {
        r += LN2 * __builtin_amdgcn_logf(accv[q].x) + 0.5f * zp[q].x * zp[q].x;
        r += LN2 * __builtin_amdgcn_logf(accv[q].y) + 0.5f * zp[q].y * zp[q].y;
    }

    // deterministic block reduction
    for (int off = 32; off > 0; off >>= 1) r += __shfl_down(r, off, 64);
    __shared__ float wsum[4];
    if ((t & 63) == 0) wsum[t >> 6] = r;
    __syncthreads();

    // last-block final reduction (deterministic: fixed-order sum over partial[])
    __shared__ int isLast;
    if (t == 0) {
        partial[bid] = (wsum[0] + wsum[1]) + (wsum[2] + wsum[3]);
        __threadfence();                          // publish partial device-wide
        const unsigned old = atomicAdd(counter, 1u);
        isLast = (old == (unsigned)(NBLK - 1));
    }
    __syncthreads();
    if (isLast) {
        __threadfence();                          // acquire all partials
        double s = 0.0;
#pragma unroll
        for (int i = 0; i < NBLK / 256; ++i) s += (double)partial[i * 256 + t];
        __shared__ double sd[256];
        sd[t] = s;
        __syncthreads();
        for (int off = 128; off > 0; off >>= 1) {
            if (t < off) sd[t] += sd[t + off];
            __syncthreads();
        }
        if (t == 0) {
            // out = total/(nc*M) - D*ln(256)
            out[0] = (float)(sd[0] * (1.0 / (double)(NC * M))
                             - (double)D * 5.545177444479562);
        }
    }
}

extern "C" void kernel_launch(void* const* d_in, const int* in_sizes, int n_in,
                              void* d_out, int out_size, void* d_ws, size_t ws_size,
                              hipStream_t stream)
{
    const float* mean   = (const float*)d_in[0];
    const float* logvar = (const float*)d_in[1];
    const float* eps    = (const float*)d_in[2];
    float* out = (float*)d_out;

    unsigned* counter = (unsigned*)d_ws;
    float*    partial = (float*)((char*)d_ws + 256);    // NBLK floats
    float4*   params  = (float4*)((char*)d_ws + 8192);  // 512KB param table

    ksetup<<<(B * D) / 256, 256, 0, stream>>>(mean, logvar, params, counter);
    kmain<<<NBLK, 256, 0, stream>>>(eps, params, partial, counter, out);
}